// Round 4
// baseline (827.468 us; speedup 1.0000x reference)
//
#include <hip/hip_runtime.h>
#include <hip/hip_bf16.h>

#define NPTS 1048576
#define NCLU 16384
#define DF   64
#define H1   128
#define H2   64
#define TPB  512                      // 8 waves
#define BPTS 256                      // points per block (32 per wave)
#define NBLK 512                      // 2 blocks/CU, persistent
#define ITERS (NPTS / (BPTS * NBLK))  // 8
#define K1P  104                      // sW1 row stride (u16): K=96 + 8 pad
#define K2P  136                      // sW2/sH row stride (u16): K=128 + 8 pad

typedef __bf16 bf16x8 __attribute__((ext_vector_type(8)));
typedef float  f32x4  __attribute__((ext_vector_type(4)));
typedef unsigned short u16x4 __attribute__((ext_vector_type(4)));
typedef unsigned short u16x8 __attribute__((ext_vector_type(8)));

__device__ __forceinline__ unsigned short f2b(float f) {
  unsigned v; __builtin_memcpy(&v, &f, 4);
  v += 0x7fffu + ((v >> 16) & 1u);          // round-to-nearest-even
  return (unsigned short)(v >> 16);
}

// pre-kernel: feat fp32 [16384][64] -> bf16 same layout in ws (halves gather bytes)
__global__ __launch_bounds__(256, 4)
void cvt_feat(const float* __restrict__ f, unsigned short* __restrict__ o) {
  int i = (blockIdx.x * 256 + threadIdx.x) * 4;
  f32x4 v = *(const f32x4*)&f[i];
  u16x4 h;
  #pragma unroll
  for (int j = 0; j < 4; ++j) h[j] = f2b(v[j]);
  *(u16x4*)&o[i] = h;
}

__global__ __launch_bounds__(TPB, 4)
void fused_gather_mlp(const float* __restrict__ feat,
                      const int* __restrict__ labels,
                      const float* __restrict__ centers,
                      const float* __restrict__ points,
                      const float* __restrict__ W1,
                      const float* __restrict__ b1,
                      const float* __restrict__ W2,
                      const float* __restrict__ b2,
                      float* __restrict__ out,
                      const unsigned short* __restrict__ featbf,
                      int use_bf)
{
  // Swapped-operand scheme: D1 = mfma(W1frag, Xfrag) = h^T tile; D2 = mfma(W2frag, Hfrag) = out^T.
  __shared__ __align__(16) unsigned short sW1[H1][K1P];    // 26,624 B  W1^T bf16 [n][k], k>=67 zeroed
  __shared__ __align__(16) unsigned short sW2[H2][K2P];    // 17,408 B  W2^T bf16 [n][k]
  __shared__ __align__(16) unsigned short sH[8][16][K2P];  // 34,816 B  per-wave 16-row h slot
  __shared__ __align__(16) float sB1f[H1];                 // 512 B
  __shared__ __align__(16) float sB2f[H2];                 // 256 B     total ~79.6 KB -> 2 blocks/CU

  const int t    = threadIdx.x;
  const int w    = t >> 6;
  const int lane = t & 63;
  const int quad = lane >> 4, l16 = lane & 15;

  // ---------------- one-time staging (conflict-free chunk-granular transpose) ----------
  if (t < 32)            *(f32x4*)&sB1f[t * 4]        = *(const f32x4*)&b1[t * 4];
  else if (t < 48)       *(f32x4*)&sB2f[(t - 32) * 4] = *(const f32x4*)&b2[(t - 32) * 4];

  #pragma unroll
  for (int i = 0; i < 3; ++i) {          // W1: 128 n x 12 kc = 1536 tasks
    int task = t + TPB * i;
    int n = task & 127, kc = task >> 7;
    u16x8 h;
    #pragma unroll
    for (int j = 0; j < 8; ++j) {
      int k = kc * 8 + j;
      h[j] = (k < 67) ? f2b(W1[k * H1 + n]) : (unsigned short)0;
    }
    *(u16x8*)&sW1[n][kc * 8] = h;
  }
  #pragma unroll
  for (int i = 0; i < 2; ++i) {          // W2: 64 n x 16 kc = 1024 tasks
    int task = t + TPB * i;
    int n = task & 63, kc = task >> 6;
    u16x8 h;
    #pragma unroll
    for (int j = 0; j < 8; ++j) h[j] = f2b(W2[(kc * 8 + j) * H2 + n]);
    *(u16x8*)&sW2[n][kc * 8] = h;
  }
  __syncthreads();                        // the only barrier

  for (int it = 0; it < ITERS; ++it) {
    const int p0 = (blockIdx.x * ITERS + it) * BPTS + w * 32;   // this wave's 32 points

    // ---- gather x fragments for both m-subtiles straight into registers (B-operand) ----
    // B-frag: lane l16 = m-local, holds X[m][ks*32 + quad*8 + j]
    bf16x8 xf[2][3];
    #pragma unroll
    for (int ms = 0; ms < 2; ++ms) {
      int p   = p0 + ms * 16 + l16;
      int lab = labels[p];
      if (use_bf) {
        u16x8 u0 = *(const u16x8*)&featbf[lab * DF + quad * 8];
        u16x8 u1 = *(const u16x8*)&featbf[lab * DF + 32 + quad * 8];
        xf[ms][0] = __builtin_bit_cast(bf16x8, u0);
        xf[ms][1] = __builtin_bit_cast(bf16x8, u1);
      } else {
        #pragma unroll
        for (int c = 0; c < 2; ++c) {
          f32x4 v0 = *(const f32x4*)&feat[lab * DF + c * 32 + quad * 8];
          f32x4 v1 = *(const f32x4*)&feat[lab * DF + c * 32 + quad * 8 + 4];
          u16x8 h;
          #pragma unroll
          for (int j = 0; j < 4; ++j) { h[j] = f2b(v0[j]); h[j + 4] = f2b(v1[j]); }
          xf[ms][c] = __builtin_bit_cast(bf16x8, h);
        }
      }
      u16x8 h2 = {0, 0, 0, 0, 0, 0, 0, 0};
      if (quad == 0) {                    // k = 64..66 coord diffs, rest zero
        #pragma unroll
        for (int j = 0; j < 3; ++j)
          h2[j] = f2b(centers[lab * 3 + j] - points[p * 3 + j]);
      }
      xf[ms][2] = __builtin_bit_cast(bf16x8, h2);
    }

    // ---- GEMM1 both subtiles, sharing every W1 fragment read ----
    f32x4 acc1[2][8];
    #pragma unroll
    for (int nt = 0; nt < 8; ++nt) {      // C-init = bias (broadcast f32x4 from LDS)
      f32x4 bv = *(const f32x4*)&sB1f[nt * 16 + quad * 4];
      acc1[0][nt] = bv; acc1[1][nt] = bv;
    }
    #pragma unroll
    for (int ks = 0; ks < 3; ++ks) {
      #pragma unroll
      for (int nt = 0; nt < 8; ++nt) {
        bf16x8 a = *(const bf16x8*)&sW1[nt * 16 + l16][ks * 32 + quad * 8];
        acc1[0][nt] = __builtin_amdgcn_mfma_f32_16x16x32_bf16(a, xf[0][ks], acc1[0][nt], 0, 0, 0);
        acc1[1][nt] = __builtin_amdgcn_mfma_f32_16x16x32_bf16(a, xf[1][ks], acc1[1][nt], 0, 0, 0);
      }
    }

    // ---- per subtile: relu->bf16->sH slot, GEMM2, relu, vectorized store ----
    #pragma unroll
    for (int ms = 0; ms < 2; ++ms) {
      // h^T C-layout: lane (quad,l16) holds h[m=l16][n=nt*16+quad*4+r] -> b64 row write
      #pragma unroll
      for (int nt = 0; nt < 8; ++nt) {
        u16x4 hv;
        #pragma unroll
        for (int r = 0; r < 4; ++r) {
          float v = acc1[ms][nt][r];
          hv[r] = f2b(v > 0.f ? v : 0.f);
        }
        *(u16x4*)&sH[w][l16][nt * 16 + quad * 4] = hv;
      }

      f32x4 acc2[4];
      #pragma unroll
      for (int nt = 0; nt < 4; ++nt)
        acc2[nt] = *(const f32x4*)&sB2f[nt * 16 + quad * 4];
      #pragma unroll
      for (int ks = 0; ks < 4; ++ks) {
        bf16x8 hb = *(const bf16x8*)&sH[w][l16][ks * 32 + quad * 8];
        #pragma unroll
        for (int nt = 0; nt < 4; ++nt) {
          bf16x8 a2 = *(const bf16x8*)&sW2[nt * 16 + l16][ks * 32 + quad * 8];
          acc2[nt] = __builtin_amdgcn_mfma_f32_16x16x32_bf16(a2, hb, acc2[nt], 0, 0, 0);
        }
      }
      // out^T C-layout: lane holds out[p=p0+ms*16+l16][n=nt*16+quad*4+r] -> dwordx4 store
      long p = p0 + ms * 16 + l16;
      #pragma unroll
      for (int nt = 0; nt < 4; ++nt) {
        f32x4 o;
        #pragma unroll
        for (int r = 0; r < 4; ++r) {
          float v = acc2[nt][r];
          o[r] = v > 0.f ? v : 0.f;
        }
        *(f32x4*)&out[p * H2 + nt * 16 + quad * 4] = o;
      }
    }
  }
}

extern "C" void kernel_launch(void* const* d_in, const int* in_sizes, int n_in,
                              void* d_out, int out_size, void* d_ws, size_t ws_size,
                              hipStream_t stream) {
  const float* feat   = (const float*)d_in[0];
  const int*   labels = (const int*)d_in[1];
  const float* cen    = (const float*)d_in[2];
  const float* pts    = (const float*)d_in[3];
  const float* W1     = (const float*)d_in[4];
  const float* b1     = (const float*)d_in[5];
  const float* W2     = (const float*)d_in[6];
  const float* b2     = (const float*)d_in[7];
  float*       outp   = (float*)d_out;

  const size_t featbf_bytes = (size_t)NCLU * DF * sizeof(unsigned short);  // 2 MB
  int use_bf = (ws_size >= featbf_bytes) ? 1 : 0;
  unsigned short* featbf = (unsigned short*)d_ws;

  if (use_bf)
    cvt_feat<<<dim3(NCLU * DF / (256 * 4)), dim3(256), 0, stream>>>(feat, featbf);

  fused_gather_mlp<<<dim3(NBLK), dim3(TPB), 0, stream>>>(
      feat, labels, cen, pts, W1, b1, W2, b2, outp, featbf, use_bf);
}